// Round 1
// 1048.835 us; speedup vs baseline: 1.1436x; 1.1436x over previous
//
#include <hip/hip_runtime.h>

// WeightedChildSumTreeLSTMEndtoEnd: BRANCH=8, DEPTH=4, N=4681, B=64, IN_DIM=MEM=256
// STARTS = {0,1,9,73,585}, COUNTS = {1,8,64,512,4096}
//
// Round 2 changes (from counters: MfmaUtil 11.5%, VALUBusy 50%, no pipe saturated):
//  - Wave tiling rebalanced: each wave now owns ALL 4 row-tiles x ONE col-tile per
//    gate (acc[g][r]) instead of 1 row-tile x 4NG col-tiles. ds_read_b128 per k-sub
//    drops from 1+4NG to 4+NG (12 MFMAs per 7 reads at NG=3, vs per 13 before).
//  - f2bf via native __bf16 cast (1 instr) instead of hand-rolled RNE (4 instr).
//  - sigmoid/tanh use v_rcp_f32 (__builtin_amdgcn_rcpf) instead of IEEE divide
//    (~8-instr div sequence without fast-math). Outputs are bf16; 1-ulp rcp is free
//    accuracy-wise.
//  LDS tiles 64 rows x 64 k bf16, row stride 72 (144 B): aligned b128, balanced banks.
//  C/D mapping: col=lane&15, row=quad*4+reg (m89-verified).

typedef unsigned short u16;
typedef unsigned int u32;
typedef __bf16 bf16x8 __attribute__((ext_vector_type(8)));
typedef float f32x4 __attribute__((ext_vector_type(4)));

#define STR 72  // bf16 elems per LDS row: 64 + 8 pad
#define NNODES 4681

__device__ __forceinline__ float bf2f(u32 lo) { return __uint_as_float(lo << 16); }
__device__ __forceinline__ u16 f2bf(float f) {
    __bf16 h = (__bf16)f;  // native v_cvt, RNE
    return *(u16*)&h;
}
__device__ __forceinline__ float rcp_(float x) { return __builtin_amdgcn_rcpf(x); }
__device__ __forceinline__ float sigm(float x) { return rcp_(1.0f + __expf(-x)); }
__device__ __forceinline__ float tanh_(float x) {
    float e = __expf(2.0f * x);
    return 1.0f - 2.0f * rcp_(e + 1.0f);
}

// Stage 64 rows x 64 k from bf16 global (row stride 256) into LDS [row][k], stride STR.
__device__ __forceinline__ void stage_bf16(u16* lds, const u16* src, int tid) {
    int row = tid >> 2, c = (tid & 3) * 16;
    const u16* p = src + (size_t)row * 256 + c;
    uint4 v0 = *(const uint4*)p;
    uint4 v1 = *(const uint4*)(p + 8);
    u16* q = lds + row * STR + c;
    *(uint4*)q = v0;
    *(uint4*)(q + 8) = v1;
}
// Same from fp32 global, converting to bf16 in-register.
__device__ __forceinline__ void stage_f32(u16* lds, const float* src, int tid) {
    int row = tid >> 2, c = (tid & 3) * 16;
    const float* p = src + (size_t)row * 256 + c;
    u16 pk[16];
#pragma unroll
    for (int q = 0; q < 4; q++) {
        float4 v = *(const float4*)(p + q * 4);
        pk[q * 4 + 0] = f2bf(v.x);
        pk[q * 4 + 1] = f2bf(v.y);
        pk[q * 4 + 2] = f2bf(v.z);
        pk[q * 4 + 3] = f2bf(v.w);
    }
    u16* q2 = lds + row * STR + c;
    *(uint4*)q2 = *(uint4*)pk;
    *(uint4*)(q2 + 8) = *(uint4*)(pk + 8);
}

// One 32-wide K-sub-step, rebalanced: 4 A-frags (all row-tiles) + NG B-frags
// (this wave's 16-col slice of each gate) -> 4*NG MFMAs.
// acc[g][r] = D[rows r*16+quad*4+reg][col wv*16+colb] for gate g.
template <int NG>
__device__ __forceinline__ void mma_ksub(const u16* As, const u16* Ws, int wv, int l,
                                         int s, f32x4 (*acc)[4]) {
    const int colb = l & 15, quad = l >> 4;
    const int ko = s * 32 + quad * 8;
    bf16x8 a[4];
#pragma unroll
    for (int r = 0; r < 4; r++)
        a[r] = *(const bf16x8*)(As + (r * 16 + colb) * STR + ko);
#pragma unroll
    for (int g = 0; g < NG; g++) {
        bf16x8 b = *(const bf16x8*)(Ws + g * (64 * STR) + (wv * 16 + colb) * STR + ko);
#pragma unroll
        for (int r = 0; r < 4; r++)
            acc[g][r] = __builtin_amdgcn_mfma_f32_16x16x32_bf16(a[r], b, acc[g][r], 0, 0, 0);
    }
}

// ---------------- weight fp32 -> bf16 conversion (once per call) ----------------
__global__ __launch_bounds__(256) void k_cvtw(
    const float* __restrict__ Wioux, const float* __restrict__ Wiouh,
    const float* __restrict__ Wfx, const float* __restrict__ Wfh,
    u16* __restrict__ out) {
    int i4 = (blockIdx.x * 256 + threadIdx.x) * 4;
    const float* p;
    if (i4 < 196608) p = Wioux + i4;
    else if (i4 < 393216) p = Wiouh + (i4 - 196608);
    else if (i4 < 458752) p = Wfx + (i4 - 393216);
    else p = Wfh + (i4 - 458752);
    float4 v = *(const float4*)p;
    u16 pk[4] = {f2bf(v.x), f2bf(v.y), f2bf(v.z), f2bf(v.w)};
    *(ushort4*)(out + i4) = *(ushort4*)pk;
}

// ---------------- Leaf: iou = X @ Wioux^T + biases; c,h ----------------
__global__ __launch_bounds__(256) void k_leaf(
    const float* __restrict__ X, const u16* __restrict__ Wxb,
    const float* __restrict__ bioux, const float* __restrict__ biouh,
    u16* __restrict__ Cp, u16* __restrict__ Hp) {
    __shared__ u16 As[64 * STR];
    __shared__ u16 Ws[3][64 * STR];
    const int tid = threadIdx.x;
    const int mem0 = blockIdx.x * 64;
    const int row0 = blockIdx.y * 64;
    const int l = tid & 63, wv = tid >> 6;
    f32x4 acc[3][4];
#pragma unroll
    for (int g = 0; g < 3; g++)
#pragma unroll
        for (int r = 0; r < 4; r++) acc[g][r] = (f32x4){0.f, 0.f, 0.f, 0.f};
    for (int kt = 0; kt < 256; kt += 64) {
        stage_f32(As, X + (size_t)row0 * 256 + kt, tid);
#pragma unroll
        for (int g = 0; g < 3; g++)
            stage_bf16(Ws[g], Wxb + ((size_t)g * 256 + mem0) * 256 + kt, tid);
        __syncthreads();
        mma_ksub<3>(As, &Ws[0][0], wv, l, 0, acc);
        mma_ksub<3>(As, &Ws[0][0], wv, l, 1, acc);
        __syncthreads();
    }
    const int colb = l & 15, quad = l >> 4;
    const int mem = mem0 + wv * 16 + colb;
    const float bi = bioux[mem] + biouh[mem];
    const float bo = bioux[256 + mem] + biouh[256 + mem];
    const float bu = bioux[512 + mem] + biouh[512 + mem];
#pragma unroll
    for (int r = 0; r < 4; r++)
#pragma unroll
        for (int reg = 0; reg < 4; reg++) {
            int row = row0 + r * 16 + quad * 4 + reg;
            float c = sigm(acc[0][r][reg] + bi) * tanh_(acc[2][r][reg] + bu);
            float h = sigm(acc[1][r][reg] + bo) * tanh_(c);
            size_t o = (size_t)row * 256 + mem;
            Cp[o] = f2bf(c);
            Hp[o] = f2bf(h);
        }
}

// ---------------- G = h_prev @ Wfh^T (raw), IN-PLACE ----------------
__global__ __launch_bounds__(256) void k_g(
    const u16* Hprev, const u16* __restrict__ Wfhb, u16* Gout) {
    __shared__ u16 As[64 * STR];
    __shared__ u16 Ws[4][64 * STR];
    const int tid = threadIdx.x;
    const int row0 = blockIdx.x * 64;
    const int l = tid & 63, wv = tid >> 6;
    f32x4 acc[4][4];
#pragma unroll
    for (int g = 0; g < 4; g++)
#pragma unroll
        for (int r = 0; r < 4; r++) acc[g][r] = (f32x4){0.f, 0.f, 0.f, 0.f};
    for (int kt = 0; kt < 256; kt += 64) {
        stage_bf16(As, Hprev + (size_t)row0 * 256 + kt, tid);
#pragma unroll
        for (int g = 0; g < 4; g++)
            stage_bf16(Ws[g], Wfhb + ((size_t)g * 64) * 256 + kt, tid);
        __syncthreads();
        mma_ksub<4>(As, &Ws[0][0], wv, l, 0, acc);
        mma_ksub<4>(As, &Ws[0][0], wv, l, 1, acc);
        __syncthreads();
    }
    const int colb = l & 15, quad = l >> 4;
#pragma unroll
    for (int g = 0; g < 4; g++)
#pragma unroll
        for (int r = 0; r < 4; r++) {
            int n = g * 64 + wv * 16 + colb;
#pragma unroll
            for (int reg = 0; reg < 4; reg++) {
                int row = row0 + r * 16 + quad * 4 + reg;
                Gout[(size_t)row * 256 + n] = f2bf(acc[g][r][reg]);
            }
        }
}

// ---------------- Main per-level: 4-gate GEMM + fused TreeLSTM epilogue ----------------
__global__ __launch_bounds__(256) void k_main(
    const float* __restrict__ X, const u16* __restrict__ Hsum,
    const u16* __restrict__ G, const u16* __restrict__ Cprev,
    const float* __restrict__ pw,
    const u16* __restrict__ Wxb, const float* __restrict__ bioux,
    const u16* __restrict__ Whb, const float* __restrict__ biouh,
    const u16* __restrict__ Wfxb, const float* __restrict__ bfx,
    const float* __restrict__ bfh,
    u16* __restrict__ Ccur, u16* __restrict__ Hcur,
    float* __restrict__ outc, float* __restrict__ outh) {
    __shared__ u16 As[64 * STR];
    __shared__ u16 Ws[4][64 * STR];
    __shared__ float pws[8];
    const int tid = threadIdx.x;
    const int mem0 = blockIdx.x * 64;
    const int lp = blockIdx.y;
    const int l = tid & 63, wv = tid >> 6;
    if (tid < 8) pws[tid] = pw[lp * 8 + tid];
    f32x4 acc[4][4];
#pragma unroll
    for (int g = 0; g < 4; g++)
#pragma unroll
        for (int r = 0; r < 4; r++) acc[g][r] = (f32x4){0.f, 0.f, 0.f, 0.f};
    // pass 1: X vs Wioux (g=0..2) and Wfx (g=3)
    for (int kt = 0; kt < 256; kt += 64) {
        stage_f32(As, X + ((size_t)lp * 64) * 256 + kt, tid);
#pragma unroll
        for (int g = 0; g < 3; g++)
            stage_bf16(Ws[g], Wxb + ((size_t)g * 256 + mem0) * 256 + kt, tid);
        stage_bf16(Ws[3], Wfxb + (size_t)mem0 * 256 + kt, tid);
        __syncthreads();
        mma_ksub<4>(As, &Ws[0][0], wv, l, 0, acc);
        mma_ksub<4>(As, &Ws[0][0], wv, l, 1, acc);
        __syncthreads();
    }
    // pass 2: Hsum vs Wiouh (g=0..2)
    for (int kt = 0; kt < 256; kt += 64) {
        stage_bf16(As, Hsum + ((size_t)lp * 64) * 256 + kt, tid);
#pragma unroll
        for (int g = 0; g < 3; g++)
            stage_bf16(Ws[g], Whb + ((size_t)g * 256 + mem0) * 256 + kt, tid);
        __syncthreads();
        mma_ksub<3>(As, &Ws[0][0], wv, l, 0, acc);
        mma_ksub<3>(As, &Ws[0][0], wv, l, 1, acc);
        __syncthreads();
    }
    // epilogue
    const int colb = l & 15, quad = l >> 4;
    const int mem = mem0 + wv * 16 + colb;
    const float bi = bioux[mem] + biouh[mem];
    const float bo = bioux[256 + mem] + biouh[256 + mem];
    const float bu = bioux[512 + mem] + biouh[512 + mem];
    const float bfv = bfx[mem] + bfh[mem];
    float cac[4][4], bff[4][4], ovv[4][4];
#pragma unroll
    for (int r = 0; r < 4; r++)
#pragma unroll
        for (int reg = 0; reg < 4; reg++) {
            cac[r][reg] = sigm(acc[0][r][reg] + bi) * tanh_(acc[2][r][reg] + bu);
            ovv[r][reg] = acc[1][r][reg] + bo;
            bff[r][reg] = bfv + acc[3][r][reg];
        }
#pragma unroll
    for (int ch = 0; ch < 8; ch++) {
        float p = pws[ch];
        size_t base = (((size_t)(lp * 8 + ch) * 64) + quad * 4) * 256 + mem;
#pragma unroll
        for (int r = 0; r < 4; r++)
#pragma unroll
            for (int reg = 0; reg < 4; reg++) {
                size_t idx = base + ((size_t)r * 16 + reg) * 256;
                float gv = bf2f((u32)G[idx]);
                float cp = bf2f((u32)Cprev[idx]);
                float f = sigm(fmaf(p, gv, bff[r][reg]));
                cac[r][reg] = fmaf(f * p, cp, cac[r][reg]);
            }
    }
#pragma unroll
    for (int r = 0; r < 4; r++)
#pragma unroll
        for (int reg = 0; reg < 4; reg++) {
            int rl = r * 16 + quad * 4 + reg;
            float h = sigm(ovv[r][reg]) * tanh_(cac[r][reg]);
            size_t o = ((size_t)lp * 64 + rl) * 256 + mem;
            Ccur[o] = f2bf(cac[r][reg]);
            Hcur[o] = f2bf(h);
            if (outc) {
                size_t oo = (size_t)rl * 256 + mem;
                outc[oo] = cac[r][reg];
                outh[oo] = h;
            }
        }
}

// ---------------- h_sum = sum_j pw_j * h_child_j ----------------
__global__ __launch_bounds__(256) void k_hsum(
    const u16* __restrict__ Hprev, const float* __restrict__ pw,
    u16* __restrict__ Hsum, int cnt) {
    int idx = blockIdx.x * 256 + threadIdx.x;
    int total = cnt * 64 * 64;
    if (idx >= total) return;
    int q = idx & 63;
    int b = (idx >> 6) & 63;
    int lp = idx >> 12;
    float s0 = 0.f, s1 = 0.f, s2 = 0.f, s3 = 0.f;
#pragma unroll
    for (int ch = 0; ch < 8; ch++) {
        float p = pw[lp * 8 + ch];
        size_t base = (((size_t)lp * 8 + ch) * 64 + b) * 256 + q * 4;
        uint2 hh = *(const uint2*)(Hprev + base);
        s0 = fmaf(p, bf2f(hh.x & 0xffffu), s0);
        s1 = fmaf(p, bf2f(hh.x >> 16), s1);
        s2 = fmaf(p, bf2f(hh.y & 0xffffu), s2);
        s3 = fmaf(p, bf2f(hh.y >> 16), s3);
    }
    u16 pk[4] = {f2bf(s0), f2bf(s1), f2bf(s2), f2bf(s3)};
    size_t o = ((size_t)lp * 64 + b) * 256 + q * 4;
    *(ushort4*)(Hsum + o) = *(ushort4*)pk;
}

// ---------------- pw gather ----------------
__global__ __launch_bounds__(256) void k_pw(
    const float* __restrict__ prob, float* __restrict__ pw, int s, int cnt) {
    int i = blockIdx.x * 256 + threadIdx.x;
    if (i < cnt * 8) {
        int lp = i >> 3, j = i & 7;
        int par = s + lp;
        pw[i] = prob[(size_t)par * NNODES + (8 * par + 1 + j)];
    }
}

extern "C" void kernel_launch(void* const* d_in, const int* in_sizes, int n_in,
                              void* d_out, int out_size, void* d_ws, size_t ws_size,
                              hipStream_t stream) {
    const float* inputs = (const float*)d_in[0];
    const float* prob   = (const float*)d_in[1];
    const float* Wioux  = (const float*)d_in[2];
    const float* bioux  = (const float*)d_in[3];
    const float* Wiouh  = (const float*)d_in[4];
    const float* biouh  = (const float*)d_in[5];
    const float* Wfx    = (const float*)d_in[6];
    const float* bfx    = (const float*)d_in[7];
    const float* Wfh    = (const float*)d_in[8];
    const float* bfh    = (const float*)d_in[9];
    float* outc = (float*)d_out;
    float* outh = outc + 64 * 256;

    // workspace layout (~305 MB + 1 MB weights)
    const size_t szA = (size_t)4096 * 64 * 256 * 2;  // 128 MiB (bf16)
    const size_t szB = (size_t)512 * 64 * 256 * 2;   // 16 MiB
    char* p = (char*)d_ws;
    u16* Ac = (u16*)p; p += szA;
    u16* Ah = (u16*)p; p += szA;
    u16* Bc = (u16*)p; p += szB;
    u16* Bh = (u16*)p; p += szB;
    u16* Hs = (u16*)p; p += szB;
    float* pwb = (float*)p; p += (size_t)512 * 8 * 4;
    u16* Wb = (u16*)p; p += (size_t)524288 * 2;
    u16* Wxb  = Wb;            // 768x256
    u16* Whb  = Wb + 196608;   // 768x256
    u16* Wfxb = Wb + 393216;   // 256x256
    u16* Wfhb = Wb + 458752;   // 256x256

    k_cvtw<<<512, 256, 0, stream>>>(Wioux, Wiouh, Wfx, Wfh, Wb);

    // leaves: nodes [585, 4681)
    k_leaf<<<dim3(4, 4096), 256, 0, stream>>>(
        inputs + (size_t)585 * 64 * 256, Wxb, bioux, biouh, Ac, Ah);

    const int starts[4] = {0, 1, 9, 73};
    const int counts[4] = {1, 8, 64, 512};
    u16 *pc = Ac, *ph = Ah, *cc = Bc, *chh = Bh;
    for (int d = 3; d >= 0; d--) {
        int s = starts[d], cnt = counts[d];
        k_pw<<<(cnt * 8 + 255) / 256, 256, 0, stream>>>(prob, pwb, s, cnt);
        k_hsum<<<(cnt * 64 * 64 + 255) / 256, 256, 0, stream>>>(ph, pwb, Hs, cnt);
        k_g<<<cnt * 8, 256, 0, stream>>>(ph, Wfhb, ph);  // in-place G over h_prev
        k_main<<<dim3(4, cnt), 256, 0, stream>>>(
            inputs + (size_t)s * 64 * 256, Hs, ph, pc, pwb,
            Wxb, bioux, Whb, biouh, Wfxb, bfx, bfh,
            cc, chh,
            (d == 0) ? outc : nullptr, (d == 0) ? outh : nullptr);
        u16* t;
        t = pc; pc = cc; cc = t;
        t = ph; ph = chh; chh = t;
    }
}

// Round 2
// 969.656 us; speedup vs baseline: 1.2370x; 1.0817x over previous
//
#include <hip/hip_runtime.h>

// WeightedChildSumTreeLSTMEndtoEnd: BRANCH=8, DEPTH=4, N=4681, B=64, IN_DIM=MEM=256
//
// Round 3: global_load_lds staging + swizzled tile images (ladder step m97 / T2).
//  - All bf16 GEMM operands (weights, H, Hsum) stored as 64x64 bf16 "tile images":
//    8 KiB blocks, byte layout row*128 + ((chunk16 ^ (row&7))*16). Producers write
//    the swizzle; global_load_lds does a LINEAR 8 KiB copy (its LDS dest is
//    wave-uniform base + lane*16 -> layout must be linear, m104); ds_read_b128
//    applies the same XOR -> conflict-free (8 lanes per 4-bank group = minimum).
//  - X (fp32) staged via in-register convert + per-lane swizzled ds_write.
//  - C buffers stay row-major (elementwise consumers only). H buffers are images.
//  - mma_ksub: 4 row-tiles x NG col-slices per wave (R1 rebalance kept).

typedef unsigned short u16;
typedef unsigned int u32;
typedef __bf16 bf16x8 __attribute__((ext_vector_type(8)));
typedef float f32x4 __attribute__((ext_vector_type(4)));

#define NNODES 4681

__device__ __forceinline__ float bf2f(u32 lo) { return __uint_as_float(lo << 16); }
__device__ __forceinline__ u16 f2bf(float f) {
    __bf16 h = (__bf16)f;
    return *(u16*)&h;
}
__device__ __forceinline__ float rcp_(float x) { return __builtin_amdgcn_rcpf(x); }
__device__ __forceinline__ float sigm(float x) { return rcp_(1.0f + __expf(-x)); }
__device__ __forceinline__ float tanh_(float x) {
    float e = __expf(2.0f * x);
    return 1.0f - 2.0f * rcp_(e + 1.0f);
}

// u16 offset of element (row, col) inside one 4096-u16 (64x64) swizzled image
__device__ __forceinline__ int img_off(int row, int col) {
    return row * 64 + (((col >> 3) ^ (row & 7)) << 3) + (col & 7);
}

// Async-copy one 8 KiB tile image global->LDS (linear; 4 waves x 2 KiB).
__device__ __forceinline__ void gll_tile(const u16* src, u16* dst, int tid) {
    const int l = tid & 63, wv = tid >> 6;
    const char* s = (const char*)src + wv * 2048 + l * 16;
    char* d = (char*)dst + wv * 2048;
    __builtin_amdgcn_global_load_lds((const __attribute__((address_space(1))) void*)s,
                                     (__attribute__((address_space(3))) void*)d, 16, 0, 0);
    __builtin_amdgcn_global_load_lds((const __attribute__((address_space(1))) void*)(s + 1024),
                                     (__attribute__((address_space(3))) void*)(d + 1024), 16, 0, 0);
}

// Stage 64 rows x 64 k from fp32 global (row stride 256) into swizzled LDS image.
__device__ __forceinline__ void stage_f32_sw(u16* lds, const float* src, int tid) {
    const int row = tid >> 2, c0 = (tid & 3) * 2;  // two 16B chunks per thread
    const float* p = src + (size_t)row * 256 + (tid & 3) * 16;
    u16 pk[16];
#pragma unroll
    for (int q = 0; q < 4; q++) {
        float4 v = *(const float4*)(p + q * 4);
        pk[q * 4 + 0] = f2bf(v.x);
        pk[q * 4 + 1] = f2bf(v.y);
        pk[q * 4 + 2] = f2bf(v.z);
        pk[q * 4 + 3] = f2bf(v.w);
    }
    const int sw = row & 7;
    *(uint4*)(lds + row * 64 + ((c0 ^ sw) << 3)) = *(uint4*)pk;
    *(uint4*)(lds + row * 64 + (((c0 + 1) ^ sw) << 3)) = *(uint4*)(pk + 8);
}

// One 32-wide K-sub-step on swizzled images: 4 A-frags + NG B-frags -> 4*NG MFMAs.
// acc[g][r]: rows r*16+quad*4+reg, col wv*16+colb of gate g. Ws tiles are 4096-u16 each.
template <int NG>
__device__ __forceinline__ void mma_ksub(const u16* As, const u16* Ws, int wv, int l,
                                         int s, f32x4 (*acc)[4]) {
    const int colb = l & 15, quad = l >> 4;
    const int c = s * 4 + quad;             // 16B chunk within the 128B k-row
    const int sc = (c ^ (colb & 7)) << 3;   // row&7 == colb&7 for all our rows
    bf16x8 a[4];
#pragma unroll
    for (int r = 0; r < 4; r++)
        a[r] = *(const bf16x8*)(As + (r * 16 + colb) * 64 + sc);
    const int boff = (wv * 16 + colb) * 64 + sc;
#pragma unroll
    for (int g = 0; g < NG; g++) {
        bf16x8 b = *(const bf16x8*)(Ws + g * 4096 + boff);
#pragma unroll
        for (int r = 0; r < 4; r++)
            acc[g][r] = __builtin_amdgcn_mfma_f32_16x16x32_bf16(a[r], b, acc[g][r], 0, 0, 0);
    }
}

// ---------------- weights fp32 -> swizzled bf16 tile images (once) ----------------
// Global n-row id: [0,768)=Wioux, [768,1536)=Wiouh, [1536,1792)=Wfx, [1792,2048)=Wfh.
// Image layout: [32 panels][4 kt][4096 u16], panel = nrow/64.
__global__ __launch_bounds__(256) void k_cvtw(
    const float* __restrict__ Wioux, const float* __restrict__ Wiouh,
    const float* __restrict__ Wfx, const float* __restrict__ Wfh,
    u16* __restrict__ out) {
    int idx = blockIdx.x * 256 + threadIdx.x;  // [0, 2048*32)
    int cc5 = idx & 31, kt = cc5 >> 3, cc = cc5 & 7;
    int rowid = idx >> 5;
    const float* src;
    if (rowid < 768) src = Wioux + (size_t)rowid * 256;
    else if (rowid < 1536) src = Wiouh + (size_t)(rowid - 768) * 256;
    else if (rowid < 1792) src = Wfx + (size_t)(rowid - 1536) * 256;
    else src = Wfh + (size_t)(rowid - 1792) * 256;
    src += kt * 64 + cc * 8;
    float4 v0 = *(const float4*)src;
    float4 v1 = *(const float4*)(src + 4);
    u16 pk[8] = {f2bf(v0.x), f2bf(v0.y), f2bf(v0.z), f2bf(v0.w),
                 f2bf(v1.x), f2bf(v1.y), f2bf(v1.z), f2bf(v1.w)};
    int r = rowid & 63;
    u16* dst = out + ((size_t)((rowid >> 6) * 4 + kt)) * 4096 + r * 64 + ((cc ^ (r & 7)) << 3);
    *(uint4*)dst = *(uint4*)pk;
}

// ---------------- Leaf: iou = X @ Wioux^T + biases; c,h ----------------
__global__ __launch_bounds__(256) void k_leaf(
    const float* __restrict__ X, const u16* __restrict__ Wp,
    const float* __restrict__ bioux, const float* __restrict__ biouh,
    u16* __restrict__ Cp, u16* __restrict__ Hp) {
    __shared__ u16 As[4096];
    __shared__ u16 Ws[3][4096];
    const int tid = threadIdx.x;
    const int bx = blockIdx.x;         // mem0 = bx*64
    const int panel = blockIdx.y;      // 64-row panel
    const int l = tid & 63, wv = tid >> 6;
    f32x4 acc[3][4];
#pragma unroll
    for (int g = 0; g < 3; g++)
#pragma unroll
        for (int r = 0; r < 4; r++) acc[g][r] = (f32x4){0.f, 0.f, 0.f, 0.f};
    for (int kt = 0; kt < 4; kt++) {
#pragma unroll
        for (int g = 0; g < 3; g++)
            gll_tile(Wp + ((size_t)((g * 4 + bx) * 4 + kt)) * 4096, Ws[g], tid);
        stage_f32_sw(As, X + (size_t)panel * 16384 + kt * 64, tid);
        __syncthreads();
        mma_ksub<3>(As, &Ws[0][0], wv, l, 0, acc);
        mma_ksub<3>(As, &Ws[0][0], wv, l, 1, acc);
        __syncthreads();
    }
    const int colb = l & 15, quad = l >> 4;
    const int j = wv * 16 + colb;        // col within this block's 64-wide slice
    const int mem = bx * 64 + j;
    const float bi = bioux[mem] + biouh[mem];
    const float bo = bioux[256 + mem] + biouh[256 + mem];
    const float bu = bioux[512 + mem] + biouh[512 + mem];
    u16* Himg = Hp + ((size_t)panel * 4 + bx) * 4096;
#pragma unroll
    for (int r = 0; r < 4; r++)
#pragma unroll
        for (int reg = 0; reg < 4; reg++) {
            int rl = r * 16 + quad * 4 + reg;
            float c = sigm(acc[0][r][reg] + bi) * tanh_(acc[2][r][reg] + bu);
            float h = sigm(acc[1][r][reg] + bo) * tanh_(c);
            Cp[((size_t)panel * 64 + rl) * 256 + mem] = f2bf(c);
            Himg[img_off(rl, j)] = f2bf(h);
        }
}

// ---------------- G = h_prev @ Wfh^T (raw), IN-PLACE (image in, row-major out) ----------------
__global__ __launch_bounds__(256) void k_g(
    const u16* Hprev, const u16* __restrict__ Wfhp, u16* Gout) {
    __shared__ u16 As[4096];
    __shared__ u16 Ws[4][4096];
    const int tid = threadIdx.x;
    const int panel = blockIdx.x;
    const int l = tid & 63, wv = tid >> 6;
    f32x4 acc[4][4];
#pragma unroll
    for (int g = 0; g < 4; g++)
#pragma unroll
        for (int r = 0; r < 4; r++) acc[g][r] = (f32x4){0.f, 0.f, 0.f, 0.f};
    for (int kt = 0; kt < 4; kt++) {
        gll_tile(Hprev + ((size_t)panel * 4 + kt) * 4096, As, tid);
#pragma unroll
        for (int g = 0; g < 4; g++)
            gll_tile(Wfhp + ((size_t)(g * 4 + kt)) * 4096, Ws[g], tid);
        __syncthreads();
        mma_ksub<4>(As, &Ws[0][0], wv, l, 0, acc);
        mma_ksub<4>(As, &Ws[0][0], wv, l, 1, acc);
        __syncthreads();
    }
    const int colb = l & 15, quad = l >> 4;
#pragma unroll
    for (int g = 0; g < 4; g++)
#pragma unroll
        for (int r = 0; r < 4; r++) {
            int n = g * 64 + wv * 16 + colb;
#pragma unroll
            for (int reg = 0; reg < 4; reg++) {
                int row = panel * 64 + r * 16 + quad * 4 + reg;
                Gout[(size_t)row * 256 + n] = f2bf(acc[g][r][reg]);
            }
        }
}

// ---------------- Main per-level: 4-gate GEMM + fused TreeLSTM epilogue ----------------
__global__ __launch_bounds__(256) void k_main(
    const float* __restrict__ X, const u16* __restrict__ Hsum,
    const u16* __restrict__ G, const u16* __restrict__ Cprev,
    const float* __restrict__ pw,
    const u16* __restrict__ Wxp, const float* __restrict__ bioux,
    const u16* __restrict__ Whp, const float* __restrict__ biouh,
    const u16* __restrict__ Wfxp, const float* __restrict__ bfx,
    const float* __restrict__ bfh,
    u16* __restrict__ Ccur, u16* __restrict__ Hcur,
    float* __restrict__ outc, float* __restrict__ outh) {
    __shared__ u16 As[4096];
    __shared__ u16 Ws[4][4096];
    __shared__ float pws[8];
    const int tid = threadIdx.x;
    const int bx = blockIdx.x;  // mem0 = bx*64
    const int lp = blockIdx.y;
    const int l = tid & 63, wv = tid >> 6;
    if (tid < 8) pws[tid] = pw[lp * 8 + tid];
    f32x4 acc[4][4];
#pragma unroll
    for (int g = 0; g < 4; g++)
#pragma unroll
        for (int r = 0; r < 4; r++) acc[g][r] = (f32x4){0.f, 0.f, 0.f, 0.f};
    // pass 1: X vs Wioux (g=0..2) and Wfx (g=3)
    for (int kt = 0; kt < 4; kt++) {
#pragma unroll
        for (int g = 0; g < 3; g++)
            gll_tile(Wxp + ((size_t)((g * 4 + bx) * 4 + kt)) * 4096, Ws[g], tid);
        gll_tile(Wfxp + ((size_t)(bx * 4 + kt)) * 4096, Ws[3], tid);
        stage_f32_sw(As, X + (size_t)lp * 16384 + kt * 64, tid);
        __syncthreads();
        mma_ksub<4>(As, &Ws[0][0], wv, l, 0, acc);
        mma_ksub<4>(As, &Ws[0][0], wv, l, 1, acc);
        __syncthreads();
    }
    // pass 2: Hsum vs Wiouh (g=0..2)
    for (int kt = 0; kt < 4; kt++) {
        gll_tile(Hsum + ((size_t)lp * 4 + kt) * 4096, As, tid);
#pragma unroll
        for (int g = 0; g < 3; g++)
            gll_tile(Whp + ((size_t)((g * 4 + bx) * 4 + kt)) * 4096, Ws[g], tid);
        __syncthreads();
        mma_ksub<3>(As, &Ws[0][0], wv, l, 0, acc);
        mma_ksub<3>(As, &Ws[0][0], wv, l, 1, acc);
        __syncthreads();
    }
    // epilogue
    const int colb = l & 15, quad = l >> 4;
    const int j = wv * 16 + colb;
    const int mem = bx * 64 + j;
    const float bi = bioux[mem] + biouh[mem];
    const float bo = bioux[256 + mem] + biouh[256 + mem];
    const float bu = bioux[512 + mem] + biouh[512 + mem];
    const float bfv = bfx[mem] + bfh[mem];
    float cac[4][4], bff[4][4], ovv[4][4];
#pragma unroll
    for (int r = 0; r < 4; r++)
#pragma unroll
        for (int reg = 0; reg < 4; reg++) {
            cac[r][reg] = sigm(acc[0][r][reg] + bi) * tanh_(acc[2][r][reg] + bu);
            ovv[r][reg] = acc[1][r][reg] + bo;
            bff[r][reg] = bfv + acc[3][r][reg];
        }
#pragma unroll
    for (int ch = 0; ch < 8; ch++) {
        float p = pws[ch];
        size_t base = (((size_t)(lp * 8 + ch) * 64) + quad * 4) * 256 + mem;
#pragma unroll
        for (int r = 0; r < 4; r++)
#pragma unroll
            for (int reg = 0; reg < 4; reg++) {
                size_t idx = base + ((size_t)r * 16 + reg) * 256;
                float gv = bf2f((u32)G[idx]);
                float cp = bf2f((u32)Cprev[idx]);
                float f = sigm(fmaf(p, gv, bff[r][reg]));
                cac[r][reg] = fmaf(f * p, cp, cac[r][reg]);
            }
    }
    u16* Himg = Hcur + ((size_t)lp * 4 + bx) * 4096;
#pragma unroll
    for (int r = 0; r < 4; r++)
#pragma unroll
        for (int reg = 0; reg < 4; reg++) {
            int rl = r * 16 + quad * 4 + reg;
            float h = sigm(ovv[r][reg]) * tanh_(cac[r][reg]);
            Ccur[((size_t)lp * 64 + rl) * 256 + mem] = f2bf(cac[r][reg]);
            Himg[img_off(rl, j)] = f2bf(h);
            if (outc) {
                size_t oo = (size_t)rl * 256 + mem;
                outc[oo] = cac[r][reg];
                outh[oo] = h;
            }
        }
}

// ---------------- h_sum = sum_j pw_j * h_child_j (image in, image out) ----------------
__global__ __launch_bounds__(256) void k_hsum(
    const u16* __restrict__ Hprev, const float* __restrict__ pw,
    u16* __restrict__ Hsum, int cnt) {
    int idx = blockIdx.x * 256 + threadIdx.x;
    if (idx >= cnt * 64 * 32) return;
    int cc5 = idx & 31, kt = cc5 >> 3, cc = cc5 & 7;
    int b = (idx >> 5) & 63;
    int lp = idx >> 11;
    const int off = b * 64 + ((cc ^ (b & 7)) << 3);
    float s[8] = {0.f, 0.f, 0.f, 0.f, 0.f, 0.f, 0.f, 0.f};
#pragma unroll
    for (int ch = 0; ch < 8; ch++) {
        float p = pw[lp * 8 + ch];
        const u16* src = Hprev + ((size_t)(lp * 8 + ch) * 4 + kt) * 4096 + off;
        uint4 hh = *(const uint4*)src;
        s[0] = fmaf(p, bf2f(hh.x & 0xffffu), s[0]);
        s[1] = fmaf(p, bf2f(hh.x >> 16), s[1]);
        s[2] = fmaf(p, bf2f(hh.y & 0xffffu), s[2]);
        s[3] = fmaf(p, bf2f(hh.y >> 16), s[3]);
        s[4] = fmaf(p, bf2f(hh.z & 0xffffu), s[4]);
        s[5] = fmaf(p, bf2f(hh.z >> 16), s[5]);
        s[6] = fmaf(p, bf2f(hh.w & 0xffffu), s[6]);
        s[7] = fmaf(p, bf2f(hh.w >> 16), s[7]);
    }
    u16 pk[8];
#pragma unroll
    for (int i = 0; i < 8; i++) pk[i] = f2bf(s[i]);
    u16* dst = Hsum + ((size_t)lp * 4 + kt) * 4096 + off;
    *(uint4*)dst = *(uint4*)pk;
}

// ---------------- pw gather ----------------
__global__ __launch_bounds__(256) void k_pw(
    const float* __restrict__ prob, float* __restrict__ pw, int s, int cnt) {
    int i = blockIdx.x * 256 + threadIdx.x;
    if (i < cnt * 8) {
        int lp = i >> 3, j = i & 7;
        int par = s + lp;
        pw[i] = prob[(size_t)par * NNODES + (8 * par + 1 + j)];
    }
}

extern "C" void kernel_launch(void* const* d_in, const int* in_sizes, int n_in,
                              void* d_out, int out_size, void* d_ws, size_t ws_size,
                              hipStream_t stream) {
    const float* inputs = (const float*)d_in[0];
    const float* prob   = (const float*)d_in[1];
    const float* Wioux  = (const float*)d_in[2];
    const float* bioux  = (const float*)d_in[3];
    const float* Wiouh  = (const float*)d_in[4];
    const float* biouh  = (const float*)d_in[5];
    const float* Wfx    = (const float*)d_in[6];
    const float* bfx    = (const float*)d_in[7];
    const float* Wfh    = (const float*)d_in[8];
    const float* bfh    = (const float*)d_in[9];
    float* outc = (float*)d_out;
    float* outh = outc + 64 * 256;

    // workspace layout (~305 MB + 1 MB weight images)
    const size_t szA = (size_t)4096 * 64 * 256 * 2;  // 128 MiB (bf16)
    const size_t szB = (size_t)512 * 64 * 256 * 2;   // 16 MiB
    char* p = (char*)d_ws;
    u16* Ac = (u16*)p; p += szA;   // C row-major
    u16* Ah = (u16*)p; p += szA;   // H tile images
    u16* Bc = (u16*)p; p += szB;
    u16* Bh = (u16*)p; p += szB;
    u16* Hs = (u16*)p; p += szB;   // Hsum tile images
    float* pwb = (float*)p; p += (size_t)512 * 8 * 4;
    u16* Wb = (u16*)p; p += (size_t)32 * 4 * 4096 * 2;  // 1 MiB of weight images
    u16* Wxp  = Wb;             // panels 0..11  (Wioux, 768 rows)
    u16* Whp  = Wb + 196608;    // panels 12..23 (Wiouh)
    u16* Wfxp = Wb + 393216;    // panels 24..27 (Wfx)
    u16* Wfhp = Wb + 458752;    // panels 28..31 (Wfh)

    k_cvtw<<<256, 256, 0, stream>>>(Wioux, Wiouh, Wfx, Wfh, Wb);

    // leaves: nodes [585, 4681)
    k_leaf<<<dim3(4, 4096), 256, 0, stream>>>(
        inputs + (size_t)585 * 64 * 256, Wxp, bioux, biouh, Ac, Ah);

    const int starts[4] = {0, 1, 9, 73};
    const int counts[4] = {1, 8, 64, 512};
    u16 *pc = Ac, *ph = Ah, *cc = Bc, *chh = Bh;
    for (int d = 3; d >= 0; d--) {
        int s = starts[d], cnt = counts[d];
        k_pw<<<(cnt * 8 + 255) / 256, 256, 0, stream>>>(prob, pwb, s, cnt);
        k_hsum<<<cnt * 8, 256, 0, stream>>>(ph, pwb, Hs, cnt);
        k_g<<<cnt * 8, 256, 0, stream>>>(ph, Wfhp, ph);  // image in, row-major G out, in-place
        k_main<<<dim3(4, cnt), 256, 0, stream>>>(
            inputs + (size_t)s * 64 * 256, Hs, ph, pc, pwb,
            Wxp, bioux, Whp, biouh, Wfxp, bfx, bfh,
            cc, chh,
            (d == 0) ? outc : nullptr, (d == 0) ? outh : nullptr);
        u16* t;
        t = pc; pc = cc; cc = t;
        t = ph; ph = chh; chh = t;
    }
}